// Round 3
// baseline (118.867 us; speedup 1.0000x reference)
//
#include <hip/hip_runtime.h>

// Four-phase decomposition:
//   K1a: one thread per (entity, gate): build 16 Rot/CRot 2x2 matrices (E*16 threads)
//   K2 : one thread per (relation, gate): same for relations (R*16 threads)
//   K1b: per entity: apply 16 precomputed gates to H^4|0>  -> estate (pure FMA)
//   K3 : per batch element: gather state_h & state_t, apply relation gates
//        via precomputed matrices, dot.  (no transcendentals anywhere hot)

struct c32 { float x, y; };

__device__ __forceinline__ c32 cmul(c32 a, c32 b) {
    return { a.x * b.x - a.y * b.y, a.x * b.y + a.y * b.x };
}
__device__ __forceinline__ c32 cadd(c32 a, c32 b) { return { a.x + b.x, a.y + b.y }; }

// PennyLane Rot(phi, theta, omega) = RZ(omega) RY(theta) RZ(phi)
__device__ __forceinline__ void make_rot(float phi, float th, float om,
                                         c32& m00, c32& m01, c32& m10, c32& m11) {
    float st, ct;
    __sincosf(0.5f * th, &st, &ct);
    float sp_, cp_;
    __sincosf(-0.5f * (phi + om), &sp_, &cp_);   // ep = exp(-0.5i(phi+omega))
    float sm_, cm_;
    __sincosf(-0.5f * (phi - om), &sm_, &cm_);   // em = exp(-0.5i(phi-omega))
    m00 = {  cp_ * ct,  sp_ * ct };
    m01 = { -cm_ * st,  sm_ * st };
    m10 = {  cm_ * st,  sm_ * st };
    m11 = {  cp_ * ct, -sp_ * ct };
}

// Build all 16 gate matrices for one param block. One thread per (block, gate).
// Output layout: mat[idx][8] = {m00.x,m00.y,m01.x,m01.y,m10.x,m10.y,m11.x,m11.y}
__global__ __launch_bounds__(256) void k_build_mats(
    const float* __restrict__ par, float* __restrict__ mats, int N) {
    const int idx = blockIdx.x * blockDim.x + threadIdx.x;
    if (idx >= N * 16) return;
    const int n = idx >> 4, g = idx & 15;
    const float* p = par + (long long)n * 48 + g * 3;
    c32 m00, m01, m10, m11;
    make_rot(p[0], p[1], p[2], m00, m01, m10, m11);
    float4* o4 = reinterpret_cast<float4*>(mats + (long long)idx * 8);
    o4[0] = make_float4(m00.x, m00.y, m01.x, m01.y);
    o4[1] = make_float4(m10.x, m10.y, m11.x, m11.y);
}

// Apply a full variational block given 16 precomputed matrices (m4 = 32 float4).
// Gate order: g<4 -> Rot on qubit g; g>=4 -> CRot(control=q, target=(q+off)%4),
// off = 1 + (g-4)/4, q = (g-4)%4.
__device__ __forceinline__ void apply_block_mats(c32* s, const float4* __restrict__ m4) {
#pragma unroll
    for (int g = 0; g < 16; ++g) {
        float4 a4 = m4[2 * g], b4 = m4[2 * g + 1];
        c32 m00 = { a4.x, a4.y }, m01 = { a4.z, a4.w };
        c32 m10 = { b4.x, b4.y }, m11 = { b4.z, b4.w };
        if (g < 4) {
            const int tmask = 1 << (3 - g);
#pragma unroll
            for (int i = 0; i < 16; ++i) {
                if ((i & tmask) == 0) {
                    c32 a = s[i], bb = s[i | tmask];
                    s[i]         = cadd(cmul(m00, a), cmul(m01, bb));
                    s[i | tmask] = cadd(cmul(m10, a), cmul(m11, bb));
                }
            }
        } else {
            const int off = 1 + ((g - 4) >> 2);
            const int q = (g - 4) & 3;
            const int tq = (q + off) & 3;
            const int cmask = 1 << (3 - q);
            const int tmask = 1 << (3 - tq);
#pragma unroll
            for (int i = 0; i < 16; ++i) {
                if ((i & cmask) != 0 && (i & tmask) == 0) {
                    c32 a = s[i], bb = s[i | tmask];
                    s[i]         = cadd(cmul(m00, a), cmul(m01, bb));
                    s[i | tmask] = cadd(cmul(m10, a), cmul(m11, bb));
                }
            }
        }
    }
}

// K1b: estate[e] = block(H^4|0>) using precomputed matrices. Pure FMA.
__global__ __launch_bounds__(256) void k1b_entity_states(
    const float* __restrict__ emat, float* __restrict__ estate, int E) {
    const int e = blockIdx.x * blockDim.x + threadIdx.x;
    if (e >= E) return;
    c32 s[16];
#pragma unroll
    for (int i = 0; i < 16; ++i) s[i] = { 0.25f, 0.0f };
    const float4* m4 = reinterpret_cast<const float4*>(emat + (long long)e * 128);
    apply_block_mats(s, m4);
    float4* o4 = reinterpret_cast<float4*>(estate + (long long)e * 32);
#pragma unroll
    for (int i = 0; i < 8; ++i)
        o4[i] = make_float4(s[2 * i].x, s[2 * i].y, s[2 * i + 1].x, s[2 * i + 1].y);
}

// K3: gather h-state, apply relation gates, dot with t-state.
__global__ __launch_bounds__(256) void k3_batch(
    const float* __restrict__ estate, const float* __restrict__ relmat,
    const int* __restrict__ h, const int* __restrict__ r, const int* __restrict__ t,
    float* __restrict__ out, int B) {
    const int b = blockIdx.x * blockDim.x + threadIdx.x;
    if (b >= B) return;

    const int hb = h[b], rb = r[b], tb = t[b];

    // Issue both state gathers up front for memory-level parallelism.
    const float4* h4 = reinterpret_cast<const float4*>(estate + (long long)hb * 32);
    const float4* t4 = reinterpret_cast<const float4*>(estate + (long long)tb * 32);
    c32 sp[16], eo[16];
#pragma unroll
    for (int i = 0; i < 8; ++i) {
        float4 hv = h4[i];
        float4 tv = t4[i];
        sp[2 * i]     = { hv.x, hv.y };
        sp[2 * i + 1] = { hv.z, hv.w };
        eo[2 * i]     = { tv.x, tv.y };
        eo[2 * i + 1] = { tv.z, tv.w };
    }

    const float4* rm4 = reinterpret_cast<const float4*>(relmat + (long long)rb * 128);
    apply_block_mats(sp, rm4);

    float acc = 0.0f;
#pragma unroll
    for (int i = 0; i < 16; ++i) acc += eo[i].x * sp[i].x + eo[i].y * sp[i].y;
    out[b] = acc;
}

extern "C" void kernel_launch(void* const* d_in, const int* in_sizes, int n_in,
                              void* d_out, int out_size, void* d_ws, size_t ws_size,
                              hipStream_t stream) {
    const float* ent = (const float*)d_in[0];
    const float* rel = (const float*)d_in[1];
    const int*   h   = (const int*)d_in[2];
    const int*   r   = (const int*)d_in[3];
    const int*   t   = (const int*)d_in[4];
    float* out = (float*)d_out;

    const int E = in_sizes[0] / 48;
    const int R = in_sizes[1] / 48;
    const int B = in_sizes[2];

    float* emat   = (float*)d_ws;                        // E * 128 floats (51.2 MB)
    float* relmat = emat + (size_t)E * 128;              // R * 128 floats (0.5 MB)
    float* estate = relmat + (size_t)R * 128;            // E * 32 floats (12.8 MB)

    k_build_mats<<<(E * 16 + 255) / 256, 256, 0, stream>>>(ent, emat, E);
    k_build_mats<<<(R * 16 + 255) / 256, 256, 0, stream>>>(rel, relmat, R);
    k1b_entity_states<<<(E + 255) / 256, 256, 0, stream>>>(emat, estate, E);
    k3_batch<<<(B + 255) / 256, 256, 0, stream>>>(estate, relmat, h, r, t, out, B);
}

// Round 4
// 98.394 us; speedup vs baseline: 1.2081x; 1.2081x over previous
//
#include <hip/hip_runtime.h>

// Two-dispatch structure (minimal HBM traffic, minimal dispatch gaps):
//   KA: fused grid — first R*16 threads build relation gate matrices;
//       remaining E threads each compute state_e = block(H^4|0>, ent[e])
//       (sincos + gate chain fused, no intermediate materialization).
//   KB: per batch element: gather state_h & state_t, apply relation block
//       via precomputed matrices (no transcendentals), dot product.
//
// ws layout: relmat [R*128 floats], estate [E*32 floats]  (~13.3 MB of 268 MB)

struct c32 { float x, y; };

__device__ __forceinline__ c32 cmul(c32 a, c32 b) {
    return { a.x * b.x - a.y * b.y, a.x * b.y + a.y * b.x };
}
__device__ __forceinline__ c32 cadd(c32 a, c32 b) { return { a.x + b.x, a.y + b.y }; }

// PennyLane Rot(phi, theta, omega) = RZ(omega) RY(theta) RZ(phi)
__device__ __forceinline__ void make_rot(float phi, float th, float om,
                                         c32& m00, c32& m01, c32& m10, c32& m11) {
    float st, ct;
    __sincosf(0.5f * th, &st, &ct);
    float sp_, cp_;
    __sincosf(-0.5f * (phi + om), &sp_, &cp_);   // ep = exp(-0.5i(phi+omega))
    float sm_, cm_;
    __sincosf(-0.5f * (phi - om), &sm_, &cm_);   // em = exp(-0.5i(phi-omega))
    m00 = {  cp_ * ct,  sp_ * ct };
    m01 = { -cm_ * st,  sm_ * st };
    m10 = {  cm_ * st,  sm_ * st };
    m11 = {  cp_ * ct, -sp_ * ct };
}

// Apply full variational block (params p[48]) to state s[16].
__device__ __forceinline__ void apply_block_params(c32* s, const float* p) {
#pragma unroll
    for (int q = 0; q < 4; ++q) {
        c32 m00, m01, m10, m11;
        make_rot(p[q * 3 + 0], p[q * 3 + 1], p[q * 3 + 2], m00, m01, m10, m11);
        const int tmask = 1 << (3 - q);
#pragma unroll
        for (int i = 0; i < 16; ++i) {
            if ((i & tmask) == 0) {
                c32 a = s[i], b = s[i | tmask];
                s[i]         = cadd(cmul(m00, a), cmul(m01, b));
                s[i | tmask] = cadd(cmul(m10, a), cmul(m11, b));
            }
        }
    }
#pragma unroll
    for (int off = 1; off <= 3; ++off) {
#pragma unroll
        for (int q = 0; q < 4; ++q) {
            const int pi = (off * 4 + q) * 3;
            c32 m00, m01, m10, m11;
            make_rot(p[pi + 0], p[pi + 1], p[pi + 2], m00, m01, m10, m11);
            const int tq = (q + off) & 3;
            const int cmask = 1 << (3 - q);
            const int tmask = 1 << (3 - tq);
#pragma unroll
            for (int i = 0; i < 16; ++i) {
                if ((i & cmask) != 0 && (i & tmask) == 0) {
                    c32 a = s[i], b = s[i | tmask];
                    s[i]         = cadd(cmul(m00, a), cmul(m01, b));
                    s[i | tmask] = cadd(cmul(m10, a), cmul(m11, b));
                }
            }
        }
    }
}

// KA: fused relation-matrix build + entity-state compute.
__global__ __launch_bounds__(256) void ka_prep(
    const float* __restrict__ ent, const float* __restrict__ rel,
    float* __restrict__ relmat, float* __restrict__ estate, int E, int R) {
    const int idx = blockIdx.x * blockDim.x + threadIdx.x;
    const int R16 = R * 16;
    if (idx < R16) {
        // Relation gate matrix: one thread per (relation, gate).
        const float* p = rel + (long long)(idx >> 4) * 48 + (idx & 15) * 3;
        c32 m00, m01, m10, m11;
        make_rot(p[0], p[1], p[2], m00, m01, m10, m11);
        float4* o4 = reinterpret_cast<float4*>(relmat + (long long)idx * 8);
        o4[0] = make_float4(m00.x, m00.y, m01.x, m01.y);
        o4[1] = make_float4(m10.x, m10.y, m11.x, m11.y);
        return;
    }
    const int e = idx - R16;
    if (e >= E) return;

    float pbuf[48];
    const float4* s4 = reinterpret_cast<const float4*>(ent + (long long)e * 48);
    float4* d4 = reinterpret_cast<float4*>(pbuf);
#pragma unroll
    for (int i = 0; i < 12; ++i) d4[i] = s4[i];

    c32 s[16];
#pragma unroll
    for (int i = 0; i < 16; ++i) s[i] = { 0.25f, 0.0f };  // H^4 |0000>
    apply_block_params(s, pbuf);

    float4* o4 = reinterpret_cast<float4*>(estate + (long long)e * 32);
#pragma unroll
    for (int i = 0; i < 8; ++i)
        o4[i] = make_float4(s[2 * i].x, s[2 * i].y, s[2 * i + 1].x, s[2 * i + 1].y);
}

// KB: per batch element — gather, apply relation gates from precomputed
// matrices, dot with t-state. No transcendentals.
__global__ __launch_bounds__(256) void kb_batch(
    const float* __restrict__ estate, const float* __restrict__ relmat,
    const int* __restrict__ h, const int* __restrict__ r, const int* __restrict__ t,
    float* __restrict__ out, int B) {
    const int b = blockIdx.x * blockDim.x + threadIdx.x;
    if (b >= B) return;

    const int hb = h[b], rb = r[b], tb = t[b];

    const float4* h4 = reinterpret_cast<const float4*>(estate + (long long)hb * 32);
    const float4* t4 = reinterpret_cast<const float4*>(estate + (long long)tb * 32);
    c32 sp[16], eo[16];
#pragma unroll
    for (int i = 0; i < 8; ++i) {
        float4 hv = h4[i];
        float4 tv = t4[i];
        sp[2 * i]     = { hv.x, hv.y };
        sp[2 * i + 1] = { hv.z, hv.w };
        eo[2 * i]     = { tv.x, tv.y };
        eo[2 * i + 1] = { tv.z, tv.w };
    }

    const float4* rm4 = reinterpret_cast<const float4*>(relmat + (long long)rb * 128);
#pragma unroll
    for (int g = 0; g < 16; ++g) {
        float4 a4 = rm4[2 * g], b4 = rm4[2 * g + 1];
        c32 m00 = { a4.x, a4.y }, m01 = { a4.z, a4.w };
        c32 m10 = { b4.x, b4.y }, m11 = { b4.z, b4.w };
        if (g < 4) {
            const int tmask = 1 << (3 - g);
#pragma unroll
            for (int i = 0; i < 16; ++i) {
                if ((i & tmask) == 0) {
                    c32 a = sp[i], bb = sp[i | tmask];
                    sp[i]         = cadd(cmul(m00, a), cmul(m01, bb));
                    sp[i | tmask] = cadd(cmul(m10, a), cmul(m11, bb));
                }
            }
        } else {
            const int off = 1 + ((g - 4) >> 2);
            const int q = (g - 4) & 3;
            const int tq = (q + off) & 3;
            const int cmask = 1 << (3 - q);
            const int tmask = 1 << (3 - tq);
#pragma unroll
            for (int i = 0; i < 16; ++i) {
                if ((i & cmask) != 0 && (i & tmask) == 0) {
                    c32 a = sp[i], bb = sp[i | tmask];
                    sp[i]         = cadd(cmul(m00, a), cmul(m01, bb));
                    sp[i | tmask] = cadd(cmul(m10, a), cmul(m11, bb));
                }
            }
        }
    }

    float acc = 0.0f;
#pragma unroll
    for (int i = 0; i < 16; ++i) acc += eo[i].x * sp[i].x + eo[i].y * sp[i].y;
    out[b] = acc;
}

extern "C" void kernel_launch(void* const* d_in, const int* in_sizes, int n_in,
                              void* d_out, int out_size, void* d_ws, size_t ws_size,
                              hipStream_t stream) {
    const float* ent = (const float*)d_in[0];
    const float* rel = (const float*)d_in[1];
    const int*   h   = (const int*)d_in[2];
    const int*   r   = (const int*)d_in[3];
    const int*   t   = (const int*)d_in[4];
    float* out = (float*)d_out;

    const int E = in_sizes[0] / 48;
    const int R = in_sizes[1] / 48;
    const int B = in_sizes[2];

    float* relmat = (float*)d_ws;                 // R * 128 floats
    float* estate = relmat + (size_t)R * 128;     // E * 32 floats

    const int ka_threads = R * 16 + E;
    ka_prep<<<(ka_threads + 255) / 256, 256, 0, stream>>>(ent, rel, relmat, estate, E, R);
    kb_batch<<<(B + 255) / 256, 256, 0, stream>>>(estate, relmat, h, r, t, out, B);
}